// Round 1
// 787.607 us; speedup vs baseline: 1.0085x; 1.0085x over previous
//
#include <hip/hip_runtime.h>

#define B_  16384
#define F_  26
#define V_  100000
#define D_  64
#define H1_ 256
#define H2_ 128
#define GR  16           // batch rows per gather block (16 rows x 16 lanes = 256 thr)
#define RPB 32           // batch rows per MLP block

__device__ __forceinline__ float sigmoidf(float x)
{
    return 1.0f / (1.0f + __expf(-x));
}

// ---------------------------------------------------------------------------
// Kernel A: embedding gather + FM second-order, high-occupancy, tiny LDS.
// thread = (row r, d-quad d4): 26 independent float4 gathers, all in flight.
// Writes fm[B][64] and fmsum[B] to workspace (fully overwritten every launch).
// ---------------------------------------------------------------------------
__global__ __launch_bounds__(256) void gather_fm_kernel(
    const int*   __restrict__ cat, const float* __restrict__ W2,
    float*       __restrict__ fm,  float*       __restrict__ fmsum)
{
    __shared__ int lidx[GR * F_];
    const int tid  = threadIdx.x;
    const int row0 = blockIdx.x * GR;

    for (int i = tid; i < GR * F_; i += 256)
        lidx[i] = cat[(size_t)row0 * F_ + i];
    __syncthreads();

    const int r  = tid >> 4;     // 0..15 local row
    const int d4 = tid & 15;     // 0..15 float4 within the 64-float row

    int idx[F_];
#pragma unroll
    for (int f = 0; f < F_; ++f) idx[f] = lidx[r * F_ + f];

    float sx = 0.f, sy = 0.f, sz = 0.f, sw = 0.f;
    float qx = 0.f, qy = 0.f, qz = 0.f, qw = 0.f;
#pragma unroll
    for (int f = 0; f < F_; ++f) {
        // 16 lanes x 16B = full 256B row, 256B-aligned; 26 independent loads/thread
        const float4 a = *reinterpret_cast<const float4*>(
            W2 + ((size_t)f * V_ + (size_t)idx[f]) * D_ + d4 * 4);
        sx += a.x; sy += a.y; sz += a.z; sw += a.w;
        qx += a.x * a.x; qy += a.y * a.y; qz += a.z * a.z; qw += a.w * a.w;
    }

    // emb = raw*0.1; fm = 0.5*(s^2 - q) on scaled -> 0.005*(s_raw^2 - q_raw)
    float4 fv;
    fv.x = 0.005f * (sx * sx - qx);
    fv.y = 0.005f * (sy * sy - qy);
    fv.z = 0.005f * (sz * sz - qz);
    fv.w = 0.005f * (sw * sw - qw);
    *reinterpret_cast<float4*>(fm + (size_t)(row0 + r) * D_ + d4 * 4) = fv;

    // per-row sum of fm over d: reduce over the 16 lanes of this row
    float p = (fv.x + fv.y) + (fv.z + fv.w);
    p += __shfl_xor(p, 1);
    p += __shfl_xor(p, 2);
    p += __shfl_xor(p, 4);
    p += __shfl_xor(p, 8);
    if (d4 == 0) fmsum[row0 + r] = p;
}

// ---------------------------------------------------------------------------
// Kernel B: MLP. 32 rows/block, 256 threads.
//  stage fm tile from global -> LDS (conflict-free b128, broadcast reads)
//  GEMM1 fm[32x64]@W1[64x256], thread=column
//  GEMM2 h1[32x256]@W2[256x128], wave=(row-half, 64 cols), butterfly reduce
// ---------------------------------------------------------------------------
__global__ __launch_bounds__(256, 2) void mlp_kernel(
    const float* __restrict__ fm_g, const float* __restrict__ fmsum_g,
    const float* __restrict__ W1,   const float* __restrict__ b1,
    const float* __restrict__ W2w,  const float* __restrict__ b2,
    const float* __restrict__ Wout, const float* __restrict__ bout,
    const float* __restrict__ bias, float* __restrict__ out)
{
    __shared__ float fms[RPB][D_];      // 8 KB, no pad: reads are uniform broadcast
    __shared__ float h1s[RPB][H1_];     // 32 KB
    __shared__ float wpart[4][16];

    const int tid  = threadIdx.x;
    const int row0 = blockIdx.x * RPB;

    // ---- stage fm tile: 32*64 floats = 512 float4 = 256 thr x 2 ----
    {
        const float4* src = reinterpret_cast<const float4*>(fm_g + (size_t)row0 * D_);
        float4*       dst = reinterpret_cast<float4*>(&fms[0][0]);
        dst[tid]       = src[tid];
        dst[tid + 256] = src[tid + 256];
    }

    // ---- GEMM1 weight column (independent of LDS stage, overlaps it) ----
    float wc[D_];
#pragma unroll
    for (int d = 0; d < D_; ++d) wc[d] = W1[d * H1_ + tid];   // coalesced, L2
    const float bc = b1[tid];

    __syncthreads();

    // ---------------- GEMM1 + sigmoid -> h1s ----------------
#pragma unroll 4
    for (int r = 0; r < RPB; ++r) {
        float a0 = bc, a1 = 0.f, a2 = 0.f, a3 = 0.f;
#pragma unroll
        for (int d4 = 0; d4 < D_ / 4; ++d4) {
            float4 fv = *reinterpret_cast<const float4*>(&fms[r][d4 * 4]); // broadcast
            a0 += fv.x * wc[d4 * 4 + 0];
            a1 += fv.y * wc[d4 * 4 + 1];
            a2 += fv.z * wc[d4 * 4 + 2];
            a3 += fv.w * wc[d4 * 4 + 3];
        }
        h1s[r][tid] = sigmoidf((a0 + a1) + (a2 + a3));
    }
    __syncthreads();

    // ---------------- GEMM2 + sigmoid*Wout, butterfly reduce ----------------
    {
        const int wid  = tid >> 6;                  // wave 0..3
        const int lane = tid & 63;
        const int half = wid >> 1;                  // rows 0..15 or 16..31
        const int c    = ((wid & 1) << 6) + lane;   // h2 column 0..127
        const int rb   = half * 16;

        const float bb = b2[c];
        float acc[16];
#pragma unroll
        for (int r = 0; r < 16; ++r) acc[r] = bb;

        for (int kc = 0; kc < H1_ / 8; ++kc) {
            float wv[8];
#pragma unroll
            for (int j = 0; j < 8; ++j) wv[j] = W2w[(kc * 8 + j) * H2_ + c]; // coalesced
#pragma unroll
            for (int r = 0; r < 16; ++r) {
                const float4* hp = reinterpret_cast<const float4*>(&h1s[rb + r][kc * 8]);
                float4 h0 = hp[0], h4 = hp[1];      // uniform LDS b128 broadcast
                acc[r] += h0.x * wv[0] + h0.y * wv[1] + h0.z * wv[2] + h0.w * wv[3]
                        + h4.x * wv[4] + h4.y * wv[5] + h4.z * wv[6] + h4.w * wv[7];
            }
        }
        const float wo = Wout[c];
#pragma unroll
        for (int r = 0; r < 16; ++r) {
            float v = sigmoidf(acc[r]) * wo;
            v += __shfl_xor(v, 32);
            v += __shfl_xor(v, 16);
            v += __shfl_xor(v, 8);
            v += __shfl_xor(v, 4);
            v += __shfl_xor(v, 2);
            v += __shfl_xor(v, 1);
            if (lane == 0) wpart[wid][r] = v;
        }
    }
    __syncthreads();

    // ---------------- final sum ----------------
    if (tid < RPB) {
        const int half = tid >> 4;
        const int r    = tid & 15;
        out[row0 + tid] = wpart[2 * half][r] + wpart[2 * half + 1][r]
                        + bout[0] + bias[0] + fmsum_g[row0 + tid];
    }
}

extern "C" void kernel_launch(void* const* d_in, const int* in_sizes, int n_in,
                              void* d_out, int out_size, void* d_ws, size_t ws_size,
                              hipStream_t stream)
{
    const int*   cat  = (const int*)  d_in[0];
    const float* W2   = (const float*)d_in[1];
    const float* W1   = (const float*)d_in[2];
    const float* b1   = (const float*)d_in[3];
    const float* W2w  = (const float*)d_in[4];
    const float* b2   = (const float*)d_in[5];
    const float* Wout = (const float*)d_in[6];
    const float* bout = (const float*)d_in[7];
    const float* bias = (const float*)d_in[8];
    float* out = (float*)d_out;

    // workspace layout: fm[B][64] (4 MB) then fmsum[B] (64 KB); every byte we
    // read in mlp_kernel is rewritten by gather_fm_kernel each launch.
    float* fm    = (float*)d_ws;
    float* fmsum = fm + (size_t)B_ * D_;

    gather_fm_kernel<<<B_ / GR, 256, 0, stream>>>(cat, W2, fm, fmsum);
    mlp_kernel<<<B_ / RPB, 256, 0, stream>>>(fm, fmsum, W1, b1, W2w, b2,
                                             Wout, bout, bias, out);
}

// Round 2
// 782.431 us; speedup vs baseline: 1.0152x; 1.0066x over previous
//
#include <hip/hip_runtime.h>

#define B_  16384
#define F_  26
#define V_  100000
#define D_  64
#define H1_ 256
#define H2_ 128
#define RPB 32           // batch rows per block

__device__ __forceinline__ float sigmoidf(float x)
{
    return 1.0f / (1.0f + __expf(-x));
}

#define ACC(av, sv, qv)                                                  \
    sv.x += av.x; sv.y += av.y; sv.z += av.z; sv.w += av.w;              \
    qv.x += av.x * av.x; qv.y += av.y * av.y;                            \
    qv.z += av.z * av.z; qv.w += av.w * av.w;

// One block = 32 batch rows, 256 threads, fully fused.
//  P1 field-phased gather+FM: thread=(row pair, 16B column), loop over fields
//     with #pragma unroll 1 + 2-deep pipeline -> instantaneous page working
//     set = ~1 field table (25.6 MB), TLB-resident, instead of all 666 MB.
//  P2 GEMM1 fm[32x64]@W1[64x256], thread=column, fm via uniform LDS broadcast
//  P3 GEMM2 h1[32x256]@W2[256x128], wave=(row-half, 64 cols), butterfly reduce
//  P4 epilogue
__global__ __launch_bounds__(256, 2) void fused_deepfm_kernel(
    const int*   __restrict__ cat,  const float* __restrict__ W2,
    const float* __restrict__ W1,   const float* __restrict__ b1,
    const float* __restrict__ W2w,  const float* __restrict__ b2,
    const float* __restrict__ Wout, const float* __restrict__ bout,
    const float* __restrict__ bias, float* __restrict__ out)
{
    __shared__ int   lidx[RPB][F_];     // 3.3 KB
    __shared__ float fms[RPB][D_];      // 8 KB   (reads are uniform broadcast)
    __shared__ float h1s[RPB][H1_];     // 32 KB
    __shared__ float fmsum[RPB];
    __shared__ float wpart[4][16];

    const int tid  = threadIdx.x;
    const int row0 = blockIdx.x * RPB;

    // ---- stage indices ----
    for (int i = tid; i < RPB * F_; i += 256)
        (&lidx[0][0])[i] = cat[(size_t)row0 * F_ + i];
    __syncthreads();

    // ---------------- P1: field-phased gather + FM second-order ----------------
    {
        const int rA   = tid >> 4;          // 0..15  -> rows rA and rA+16
        const int rB   = rA + 16;
        const int d4   = tid & 15;          // 16B column within the 256B row
        const size_t doff = (size_t)(d4 * 4);
        const size_t VD   = (size_t)V_ * (size_t)D_;

        float4 sA = {0,0,0,0}, qA = {0,0,0,0};
        float4 sB = {0,0,0,0}, qB = {0,0,0,0};

        // 2-deep pipeline prologue: fields 0 and 1
        const float* fb = W2;
        float4 aA = *reinterpret_cast<const float4*>(fb + (size_t)lidx[rA][0] * D_ + doff);
        float4 aB = *reinterpret_cast<const float4*>(fb + (size_t)lidx[rB][0] * D_ + doff);
        fb += VD;
        float4 bA = *reinterpret_cast<const float4*>(fb + (size_t)lidx[rA][1] * D_ + doff);
        float4 bB = *reinterpret_cast<const float4*>(fb + (size_t)lidx[rB][1] * D_ + doff);
        fb += VD;

        // steady state: issue field f+2, consume field f.  unroll 1 keeps the
        // TLB window at ~2 consecutive field tables.
#pragma unroll 1
        for (int f = 0; f < F_ - 2; ++f) {
            float4 cA = *reinterpret_cast<const float4*>(fb + (size_t)lidx[rA][f + 2] * D_ + doff);
            float4 cB = *reinterpret_cast<const float4*>(fb + (size_t)lidx[rB][f + 2] * D_ + doff);
            ACC(aA, sA, qA); ACC(aB, sB, qB);
            aA = bA; aB = bB; bA = cA; bB = cB;
            fb += VD;
        }
        ACC(aA, sA, qA); ACC(aB, sB, qB);   // field 24
        ACC(bA, sA, qA); ACC(bB, sB, qB);   // field 25

        // emb = raw*0.1; fm = 0.5*(s^2 - q) scaled -> 0.005*(s_raw^2 - q_raw)
        float4 g0, g1;
        g0.x = 0.005f * (sA.x * sA.x - qA.x); g0.y = 0.005f * (sA.y * sA.y - qA.y);
        g0.z = 0.005f * (sA.z * sA.z - qA.z); g0.w = 0.005f * (sA.w * sA.w - qA.w);
        g1.x = 0.005f * (sB.x * sB.x - qB.x); g1.y = 0.005f * (sB.y * sB.y - qB.y);
        g1.z = 0.005f * (sB.z * sB.z - qB.z); g1.w = 0.005f * (sB.w * sB.w - qB.w);

        *reinterpret_cast<float4*>(&fms[rA][d4 * 4]) = g0;
        *reinterpret_cast<float4*>(&fms[rB][d4 * 4]) = g1;

        // per-row sum over d: reduce across the 16 lanes owning this row
        float pA = (g0.x + g0.y) + (g0.z + g0.w);
        float pB = (g1.x + g1.y) + (g1.z + g1.w);
        pA += __shfl_xor(pA, 1); pA += __shfl_xor(pA, 2);
        pA += __shfl_xor(pA, 4); pA += __shfl_xor(pA, 8);
        pB += __shfl_xor(pB, 1); pB += __shfl_xor(pB, 2);
        pB += __shfl_xor(pB, 4); pB += __shfl_xor(pB, 8);
        if (d4 == 0) { fmsum[rA] = pA; fmsum[rB] = pB; }
    }

    // ---- GEMM1 weight column: issue before the barrier so it overlaps the
    //      tail of other waves' gather ----
    float wc[D_];
#pragma unroll
    for (int d = 0; d < D_; ++d) wc[d] = W1[d * H1_ + tid];   // coalesced, L2
    const float bc = b1[tid];

    __syncthreads();

    // ---------------- P2: GEMM1 + sigmoid -> h1s ----------------
#pragma unroll 4
    for (int r = 0; r < RPB; ++r) {
        float a0 = bc, a1 = 0.f, a2 = 0.f, a3 = 0.f;
#pragma unroll
        for (int d4 = 0; d4 < D_ / 4; ++d4) {
            float4 fv = *reinterpret_cast<const float4*>(&fms[r][d4 * 4]); // broadcast
            a0 += fv.x * wc[d4 * 4 + 0];
            a1 += fv.y * wc[d4 * 4 + 1];
            a2 += fv.z * wc[d4 * 4 + 2];
            a3 += fv.w * wc[d4 * 4 + 3];
        }
        h1s[r][tid] = sigmoidf((a0 + a1) + (a2 + a3));
    }
    __syncthreads();

    // ---------------- P3: GEMM2 + sigmoid*Wout, butterfly reduce ----------------
    {
        const int wid  = tid >> 6;                  // wave 0..3
        const int lane = tid & 63;
        const int half = wid >> 1;                  // rows 0..15 or 16..31
        const int c    = ((wid & 1) << 6) + lane;   // h2 column 0..127
        const int rb   = half * 16;

        const float bb = b2[c];
        float acc[16];
#pragma unroll
        for (int r = 0; r < 16; ++r) acc[r] = bb;

        for (int kc = 0; kc < H1_ / 8; ++kc) {
            float wv[8];
#pragma unroll
            for (int j = 0; j < 8; ++j) wv[j] = W2w[(kc * 8 + j) * H2_ + c]; // coalesced
#pragma unroll
            for (int r = 0; r < 16; ++r) {
                const float4* hp = reinterpret_cast<const float4*>(&h1s[rb + r][kc * 8]);
                float4 h0 = hp[0], h4 = hp[1];      // uniform LDS b128 broadcast
                acc[r] += h0.x * wv[0] + h0.y * wv[1] + h0.z * wv[2] + h0.w * wv[3]
                        + h4.x * wv[4] + h4.y * wv[5] + h4.z * wv[6] + h4.w * wv[7];
            }
        }
        const float wo = Wout[c];
#pragma unroll
        for (int r = 0; r < 16; ++r) {
            float v = sigmoidf(acc[r]) * wo;
            v += __shfl_xor(v, 32);
            v += __shfl_xor(v, 16);
            v += __shfl_xor(v, 8);
            v += __shfl_xor(v, 4);
            v += __shfl_xor(v, 2);
            v += __shfl_xor(v, 1);
            if (lane == 0) wpart[wid][r] = v;
        }
    }
    __syncthreads();

    // ---------------- P4: final sum ----------------
    if (tid < RPB) {
        const int half = tid >> 4;
        const int r    = tid & 15;
        out[row0 + tid] = wpart[2 * half][r] + wpart[2 * half + 1][r]
                        + bout[0] + bias[0] + fmsum[tid];
    }
}

extern "C" void kernel_launch(void* const* d_in, const int* in_sizes, int n_in,
                              void* d_out, int out_size, void* d_ws, size_t ws_size,
                              hipStream_t stream)
{
    const int*   cat  = (const int*)  d_in[0];
    const float* W2   = (const float*)d_in[1];
    const float* W1   = (const float*)d_in[2];
    const float* b1   = (const float*)d_in[3];
    const float* W2w  = (const float*)d_in[4];
    const float* b2   = (const float*)d_in[5];
    const float* Wout = (const float*)d_in[6];
    const float* bout = (const float*)d_in[7];
    const float* bias = (const float*)d_in[8];
    float* out = (float*)d_out;

    fused_deepfm_kernel<<<B_ / RPB, 256, 0, stream>>>(
        cat, W2, W1, b1, W2w, b2, Wout, bout, bias, out);
}

// Round 3
// 761.003 us; speedup vs baseline: 1.0438x; 1.0282x over previous
//
#include <hip/hip_runtime.h>

#define B_  16384
#define F_  26
#define V_  100000
#define D_  64
#define H1_ 256
#define H2_ 128
#define RPB 16           // batch rows per block (256 thr = 16 rows x 16 lanes)

typedef float f32x4 __attribute__((ext_vector_type(4)));

__device__ __forceinline__ float sigmoidf(float x)
{
    return 1.0f / (1.0f + __expf(-x));
}

// One block = 16 batch rows, 256 threads, fully fused, 4 blocks/CU resident
// (LDS ~22 KB, VGPR capped via __launch_bounds__(256,4)) so the gather phase
// of some blocks overlaps the MLP phase of others on the same CU.
//  P1 gather+FM: thread=(row, 16B col), 26 independent NON-TEMPORAL float4
//     loads (single-use rows -> don't sweep L2/L3)
//  P2 GEMM1 fm[16x64]@W1[64x256], thread=column, fm via uniform LDS broadcast
//  P3 GEMM2 h1[16x256]@W2[256x128], wave=(8-row half, 64 cols), butterfly
//  P4 epilogue
__global__ __launch_bounds__(256, 4) void fused_deepfm_kernel(
    const int*   __restrict__ cat,  const float* __restrict__ W2,
    const float* __restrict__ W1,   const float* __restrict__ b1,
    const float* __restrict__ W2w,  const float* __restrict__ b2,
    const float* __restrict__ Wout, const float* __restrict__ bout,
    const float* __restrict__ bias, float* __restrict__ out)
{
    __shared__ int   lidx[RPB][F_];     // 1.7 KB
    __shared__ float fms[RPB][D_];      // 4 KB   (reads are uniform broadcast)
    __shared__ float h1s[RPB][H1_];     // 16 KB
    __shared__ float fmsum[RPB];
    __shared__ float wpart[4][8];

    const int tid  = threadIdx.x;
    const int row0 = blockIdx.x * RPB;

    // ---- stage indices (coalesced) ----
    for (int i = tid; i < RPB * F_; i += 256)
        (&lidx[0][0])[i] = cat[(size_t)row0 * F_ + i];
    __syncthreads();

    // ---------------- P1: gather + FM second-order ----------------
    {
        const int r  = tid >> 4;        // 0..15 local row
        const int d4 = tid & 15;        // 16B column within the 256B row
        const size_t doff = (size_t)(d4 * 4);

        float4 s = {0.f, 0.f, 0.f, 0.f}, q = {0.f, 0.f, 0.f, 0.f};
#pragma unroll
        for (int f = 0; f < F_; ++f) {
            // 16 lanes x 16B = full 256B row; rows are single-use -> nt load
            const f32x4* p = reinterpret_cast<const f32x4*>(
                W2 + ((size_t)f * V_ + (size_t)lidx[r][f]) * D_ + doff);
            f32x4 a = __builtin_nontemporal_load(p);
            s.x += a.x; s.y += a.y; s.z += a.z; s.w += a.w;
            q.x += a.x * a.x; q.y += a.y * a.y;
            q.z += a.z * a.z; q.w += a.w * a.w;
        }

        // emb = raw*0.1; fm = 0.5*(s^2 - q) scaled -> 0.005*(s_raw^2 - q_raw)
        float4 g;
        g.x = 0.005f * (s.x * s.x - q.x);
        g.y = 0.005f * (s.y * s.y - q.y);
        g.z = 0.005f * (s.z * s.z - q.z);
        g.w = 0.005f * (s.w * s.w - q.w);
        *reinterpret_cast<float4*>(&fms[r][d4 * 4]) = g;

        // per-row sum over d: reduce across the 16 lanes owning this row
        float p = (g.x + g.y) + (g.z + g.w);
        p += __shfl_xor(p, 1);
        p += __shfl_xor(p, 2);
        p += __shfl_xor(p, 4);
        p += __shfl_xor(p, 8);
        if (d4 == 0) fmsum[r] = p;
    }

    // ---- GEMM1 weight column: issue before barrier, overlaps gather tail ----
    float wc[D_];
#pragma unroll
    for (int d = 0; d < D_; ++d) wc[d] = W1[d * H1_ + tid];   // coalesced, L2
    const float bc = b1[tid];

    __syncthreads();

    // ---------------- P2: GEMM1 + sigmoid -> h1s ----------------
#pragma unroll 4
    for (int r = 0; r < RPB; ++r) {
        float a0 = bc, a1 = 0.f, a2 = 0.f, a3 = 0.f;
#pragma unroll
        for (int d4 = 0; d4 < D_ / 4; ++d4) {
            float4 fv = *reinterpret_cast<const float4*>(&fms[r][d4 * 4]); // broadcast
            a0 += fv.x * wc[d4 * 4 + 0];
            a1 += fv.y * wc[d4 * 4 + 1];
            a2 += fv.z * wc[d4 * 4 + 2];
            a3 += fv.w * wc[d4 * 4 + 3];
        }
        h1s[r][tid] = sigmoidf((a0 + a1) + (a2 + a3));
    }
    __syncthreads();

    // ---------------- P3: GEMM2 + sigmoid*Wout, butterfly reduce ----------------
    {
        const int wid  = tid >> 6;                  // wave 0..3
        const int lane = tid & 63;
        const int c    = ((wid & 1) << 6) + lane;   // h2 column 0..127
        const int rb   = (wid >> 1) * 8;            // rows 0..7 or 8..15

        const float bb = b2[c];
        float acc[8];
#pragma unroll
        for (int r = 0; r < 8; ++r) acc[r] = bb;

        for (int kc = 0; kc < H1_ / 8; ++kc) {
            float wv[8];
#pragma unroll
            for (int j = 0; j < 8; ++j) wv[j] = W2w[(kc * 8 + j) * H2_ + c]; // coalesced
#pragma unroll
            for (int r = 0; r < 8; ++r) {
                const float4* hp = reinterpret_cast<const float4*>(&h1s[rb + r][kc * 8]);
                float4 h0 = hp[0], h4 = hp[1];      // uniform LDS b128 broadcast
                acc[r] += h0.x * wv[0] + h0.y * wv[1] + h0.z * wv[2] + h0.w * wv[3]
                        + h4.x * wv[4] + h4.y * wv[5] + h4.z * wv[6] + h4.w * wv[7];
            }
        }
        const float wo = Wout[c];
#pragma unroll
        for (int r = 0; r < 8; ++r) {
            float v = sigmoidf(acc[r]) * wo;
            v += __shfl_xor(v, 32);
            v += __shfl_xor(v, 16);
            v += __shfl_xor(v, 8);
            v += __shfl_xor(v, 4);
            v += __shfl_xor(v, 2);
            v += __shfl_xor(v, 1);
            if (lane == 0) wpart[wid][r] = v;
        }
    }
    __syncthreads();

    // ---------------- P4: final sum ----------------
    if (tid < RPB) {
        const int hh = tid >> 3;            // 0: rows 0-7, 1: rows 8-15
        const int r  = tid & 7;
        out[row0 + tid] = wpart[2 * hh][r] + wpart[2 * hh + 1][r]
                        + bout[0] + bias[0] + fmsum[tid];
    }
}

extern "C" void kernel_launch(void* const* d_in, const int* in_sizes, int n_in,
                              void* d_out, int out_size, void* d_ws, size_t ws_size,
                              hipStream_t stream)
{
    const int*   cat  = (const int*)  d_in[0];
    const float* W2   = (const float*)d_in[1];
    const float* W1   = (const float*)d_in[2];
    const float* b1   = (const float*)d_in[3];
    const float* W2w  = (const float*)d_in[4];
    const float* b2   = (const float*)d_in[5];
    const float* Wout = (const float*)d_in[6];
    const float* bout = (const float*)d_in[7];
    const float* bias = (const float*)d_in[8];
    float* out = (float*)d_out;

    fused_deepfm_kernel<<<B_ / RPB, 256, 0, stream>>>(
        cat, W2, W1, b1, W2w, b2, Wout, bout, bias, out);
}